// Round 9
// baseline (44.391 us; speedup 1.0000x reference)
//
#include <hip/hip_runtime.h>

#define N_BATCH 4096
#define NCELL (4096 * 14 * 14)   // 802816
#define CPB 128                  // cells per block == threads per block
#define NBLOCKS (NCELL / CPB)    // 6272

// 1/14; reference does x/14.0f. Verified absmax 0.0 with reciprocal-mul.
#define INV_S 0.07142857142857142f

// ---------------------------------------------------------------------------
// Kernel 1: detect mask storage layout.
// flag: 0 = int32 (0/1), 1 = float32 (0.0/1.0), 2 = uint8 (numpy bool)
// ---------------------------------------------------------------------------
__global__ void detect_flag(const unsigned int* __restrict__ mask_words,
                            int* __restrict__ flag) {
    __shared__ int s_notInt, s_notFloat;
    const int tid = threadIdx.x;
    if (tid == 0) { s_notInt = 0; s_notFloat = 0; }
    __syncthreads();
    int notInt = 0, notFloat = 0;
    for (int i = tid; i < 1024; i += 256) {
        const unsigned int u = mask_words[i];
        if (u > 1u) notInt = 1;
        if (u != 0u && u != 0x3F800000u) notFloat = 1;
    }
    if (notInt)   atomicOr(&s_notInt, 1);
    if (notFloat) atomicOr(&s_notFloat, 1);
    __syncthreads();
    if (tid == 0) *flag = (!s_notInt) ? 0 : ((!s_notFloat) ? 1 : 2);
}

// ---------------------------------------------------------------------------
// async global->LDS 16B stage: global src is per-lane, LDS dest is wave-
// uniform base + lane*16. Zero VGPR cost per stage.
// ---------------------------------------------------------------------------
__device__ __forceinline__ void stage16(const float4* g_lane, float4* l_wavebase, int lane) {
#if __has_builtin(__builtin_amdgcn_global_load_lds)
    __builtin_amdgcn_global_load_lds((const __attribute__((address_space(1))) void*)g_lane,
                                     (__attribute__((address_space(3))) void*)l_wavebase,
                                     16, 0, 0);
#else
    l_wavebase[lane] = *g_lane;
#endif
}

__device__ __forceinline__ float iou_xyxy(const float a0, const float a1,
                                          const float a2, const float a3,
                                          const float b0, const float b1,
                                          const float b2, const float b3) {
    const float ltx = fmaxf(a0, b0), lty = fmaxf(a1, b1);
    const float rbx = fminf(a2, b2), rby = fminf(a3, b3);
    const float wx = fmaxf(rbx - ltx, 0.0f), wy = fmaxf(rby - lty, 0.0f);
    const float inter = wx * wy;
    const float area_a = (a2 - a0) * (a3 - a1);
    const float area_b = (b2 - b0) * (b3 - b1);
    return inter / (area_a + area_b - inter);
}

// ---------------------------------------------------------------------------
// Kernel 2: main loss. Block = 128 cells / 128 threads (2 waves), 15.9 KB LDS
// -> up to ~10 blocks/CU resident. pred -> LDS via async global_load_lds;
// tcls/tbox/mask in registers; one barrier; one float4 partial per block.
// ---------------------------------------------------------------------------
__global__ __launch_bounds__(128) void yolo_loss_main(
    const float* __restrict__ pred,
    const float* __restrict__ tbox,
    const float* __restrict__ tcls,
    const void* __restrict__ maskp,
    const int* __restrict__ flagp,
    float4* __restrict__ partial) {

    __shared__ __align__(16) float s_pred[CPB * 30];  // 15 KB
    __shared__ float s_mf[CPB];                       // 0.5 KB
    __shared__ float s_red[4][2];

    const int t = threadIdx.x;
    const int lane = t & 63;
    const int cell0 = blockIdx.x * CPB;
    const int idx = cell0 + t;
    const int flag = *flagp;

    // ---- async stage pred -> LDS (960 float4 = 7.5 * 128) ----
    const float4* pg = (const float4*)(pred + (size_t)cell0 * 30);
    float4* sp4 = (float4*)s_pred;
    const int wbase = t & ~63;   // 0 or 64
    #pragma unroll
    for (int k = 0; k < 7; ++k)
        stage16(pg + k * 128 + t, sp4 + k * 128 + wbase, lane);
    if (t < 64)                  // tail 64 float4s, wave 0 fully active
        stage16(pg + 896 + t, sp4 + 896, lane);

    // ---- tcls into registers (640 float4 = 5 * 128), overlaps stages ----
    const float4* cg = (const float4*)(tcls + (size_t)cell0 * 20);
    const float4 c0 = cg[t];
    const float4 c1 = cg[t + 128];
    const float4 c2 = cg[t + 256];
    const float4 c3 = cg[t + 384];
    const float4 c4 = cg[t + 512];

    const float4 tb = ((const float4*)tbox)[idx];

    bool m;
    if (flag == 0)      m = ((const int*)maskp)[idx] != 0;
    else if (flag == 1) m = ((const float*)maskp)[idx] != 0.0f;
    else                m = ((const unsigned char*)maskp)[idx] != 0;
    const float mf = m ? 1.0f : 0.0f;
    s_mf[t] = mf;

    __syncthreads();   // drains vmcnt (async stages) + lgkmcnt

    // ---- phase 2: cls loss, tcls registers vs LDS pred ----
    float cls = 0.0f;
    {
        #define CLS_STEP(K, CK)                                        \
        {                                                              \
            const int e  = t + (K) * 128;                              \
            const int c  = e / 5;                                      \
            const int j0 = (e - c * 5) * 4;                            \
            const float* sp = &s_pred[c * 30 + 10 + j0];               \
            const float w = s_mf[c];                                   \
            const float d0 = sp[0] - (CK).x;                           \
            const float d1 = sp[1] - (CK).y;                           \
            const float d2 = sp[2] - (CK).z;                           \
            const float d3 = sp[3] - (CK).w;                           \
            cls += w * (d0 * d0 + d1 * d1 + d2 * d2 + d3 * d3);        \
        }
        CLS_STEP(0, c0) CLS_STEP(1, c1) CLS_STEP(2, c2)
        CLS_STEP(3, c3) CLS_STEP(4, c4)
        #undef CLS_STEP
    }

    // ---- phase 3: per-cell box math from LDS ----
    float pr[10];
    #pragma unroll
    for (int i = 0; i < 10; ++i) pr[i] = s_pred[t * 30 + i];

    float noobj = (1.0f - mf) * (pr[4] * pr[4] + pr[9] * pr[9]);

    const float b1x0 = pr[0] * INV_S - 0.5f * pr[2];
    const float b1y0 = pr[1] * INV_S - 0.5f * pr[3];
    const float b1x1 = pr[0] * INV_S + 0.5f * pr[2];
    const float b1y1 = pr[1] * INV_S + 0.5f * pr[3];
    const float b2x0 = pr[5] * INV_S - 0.5f * pr[7];
    const float b2y0 = pr[6] * INV_S - 0.5f * pr[8];
    const float b2x1 = pr[5] * INV_S + 0.5f * pr[7];
    const float b2y1 = pr[6] * INV_S + 0.5f * pr[8];
    const float btx0 = tb.x * INV_S - 0.5f * tb.z;
    const float bty0 = tb.y * INV_S - 0.5f * tb.w;
    const float btx1 = tb.x * INV_S + 0.5f * tb.z;
    const float bty1 = tb.y * INV_S + 0.5f * tb.w;

    const float i1 = iou_xyxy(b1x0, b1y0, b1x1, b1y1, btx0, bty0, btx1, bty1);
    const float i2 = iou_xyxy(b2x0, b2y0, b2x1, b2y1, btx0, bty0, btx1, bty1);

    const bool take1 = i1 > i2;
    const float best_iou = take1 ? i1 : i2;
    const float bx = take1 ? pr[0] : pr[5];
    const float by = take1 ? pr[1] : pr[6];
    const float bw = take1 ? pr[2] : pr[7];
    const float bh = take1 ? pr[3] : pr[8];
    const float bc = take1 ? pr[4] : pr[9];

    const float dx = bx - tb.x;
    const float dy = by - tb.y;
    const float pw = m ? sqrtf(bw) : 1.0f;
    const float ph = m ? sqrtf(bh) : 1.0f;
    const float tw = m ? sqrtf(tb.z) : 1.0f;
    const float th = m ? sqrtf(tb.w) : 1.0f;
    float reg = mf * (dx * dx + dy * dy)
              + mf * ((pw - tw) * (pw - tw) + (ph - th) * (ph - th));

    const float dc = bc - best_iou;
    float conf = mf * dc * dc;

    // ---- wave + block reduction (2 waves) ----
    #pragma unroll
    for (int off = 32; off > 0; off >>= 1) {
        reg   += __shfl_down(reg,   off);
        conf  += __shfl_down(conf,  off);
        noobj += __shfl_down(noobj, off);
        cls   += __shfl_down(cls,   off);
    }
    const int wid = t >> 6;
    if (lane == 0) {
        s_red[0][wid] = reg; s_red[1][wid] = conf;
        s_red[2][wid] = noobj; s_red[3][wid] = cls;
    }
    __syncthreads();
    if (t == 0) {
        partial[blockIdx.x] = make_float4(s_red[0][0] + s_red[0][1],
                                          s_red[1][0] + s_red[1][1],
                                          s_red[2][0] + s_red[2][1],
                                          s_red[3][0] + s_red[3][1]);
    }
}

// ---------------------------------------------------------------------------
// Kernel 3: finalize — reduce block partials (double accum), normalize.
// ---------------------------------------------------------------------------
__global__ __launch_bounds__(256) void yolo_finalize(
    const float4* __restrict__ partial,
    float* __restrict__ out) {
    const int t = threadIdx.x;
    double r = 0.0, cf = 0.0, no = 0.0, cl = 0.0;
    for (int i = t; i < NBLOCKS; i += 256) {
        const float4 p = partial[i];
        r += (double)p.x; cf += (double)p.y; no += (double)p.z; cl += (double)p.w;
    }
    #pragma unroll
    for (int off = 32; off > 0; off >>= 1) {
        r  += __shfl_down(r,  off);
        cf += __shfl_down(cf, off);
        no += __shfl_down(no, off);
        cl += __shfl_down(cl, off);
    }
    __shared__ double s[4][4];
    const int lane = t & 63;
    const int wid  = t >> 6;
    if (lane == 0) { s[0][wid] = r; s[1][wid] = cf; s[2][wid] = no; s[3][wid] = cl; }
    __syncthreads();
    if (t == 0) {
        double R = 0, CF = 0, NO = 0, CL = 0;
        #pragma unroll
        for (int w = 0; w < 4; ++w) { R += s[0][w]; CF += s[1][w]; NO += s[2][w]; CL += s[3][w]; }
        const float invN = 1.0f / (float)N_BATCH;
        const float reg   = (float)R  * invN;
        const float conf  = (float)CF * invN;
        const float noobj = (float)NO * invN;
        const float cls   = (float)CL * invN;
        out[0] = 5.0f * reg + conf + 0.5f * noobj + cls;
        out[1] = reg;
        out[2] = conf;
        out[3] = noobj;
        out[4] = cls;
    }
}

extern "C" void kernel_launch(void* const* d_in, const int* in_sizes, int n_in,
                              void* d_out, int out_size, void* d_ws, size_t ws_size,
                              hipStream_t stream) {
    const float* pred = (const float*)d_in[0];
    const float* tbox = (const float*)d_in[1];
    const float* tcls = (const float*)d_in[2];
    const void*  mask = (const void*)d_in[3];
    float* out = (float*)d_out;

    float4* partial = (float4*)d_ws;                      // 6272 * 16 B = 100 KB
    int* flag = (int*)((char*)d_ws + NBLOCKS * sizeof(float4));

    detect_flag<<<1, 256, 0, stream>>>((const unsigned int*)mask, flag);
    yolo_loss_main<<<NBLOCKS, 128, 0, stream>>>(pred, tbox, tcls, mask, flag, partial);
    yolo_finalize<<<1, 256, 0, stream>>>(partial, out);
}

// Round 10
// 36.230 us; speedup vs baseline: 1.2253x; 1.2253x over previous
//
#include <hip/hip_runtime.h>

#define N_BATCH 4096
#define NCELL (4096 * 14 * 14)   // 802816
#define CPB 256                  // cells per block (4 waves x 64 cells)
#define NBLOCKS (NCELL / CPB)    // 3136

// 1/14; reference does x/14.0f. Verified absmax 0.0 with reciprocal-mul.
#define INV_S 0.07142857142857142f

// ---------------------------------------------------------------------------
// async global->LDS 16B stage: global src per-lane, LDS dest wave-uniform
// base + lane*16. Zero VGPR cost; respects exec mask for tail stages.
// ---------------------------------------------------------------------------
__device__ __forceinline__ void stage16(const float4* g_lane, float4* l_wavebase, int lane) {
#if __has_builtin(__builtin_amdgcn_global_load_lds)
    __builtin_amdgcn_global_load_lds((const __attribute__((address_space(1))) void*)g_lane,
                                     (__attribute__((address_space(3))) void*)l_wavebase,
                                     16, 0, 0);
#else
    l_wavebase[lane] = *g_lane;
#endif
}

__device__ __forceinline__ float iou_xyxy(const float a0, const float a1,
                                          const float a2, const float a3,
                                          const float b0, const float b1,
                                          const float b2, const float b3) {
    const float ltx = fmaxf(a0, b0), lty = fmaxf(a1, b1);
    const float rbx = fminf(a2, b2), rby = fminf(a3, b3);
    const float wx = fmaxf(rbx - ltx, 0.0f), wy = fmaxf(rby - lty, 0.0f);
    const float inter = wx * wy;
    const float area_a = (a2 - a0) * (a3 - a1);
    const float area_b = (b2 - b0) * (b3 - b1);
    return inter / (area_a + area_b - inter);
}

// ---------------------------------------------------------------------------
// Kernel 1: main loss. Each WAVE owns an independent 64-cell tile: private
// 7.5 KB LDS slice (async-staged pred), register tcls/tbox/mask, in-wave
// flag detection via ballot on the (L2-broadcast) first 256 mask bytes.
// NO barrier on the data path — only the final 4-wave partial combine.
// ---------------------------------------------------------------------------
__global__ __launch_bounds__(256) void yolo_loss_main(
    const float* __restrict__ pred,
    const float* __restrict__ tbox,
    const float* __restrict__ tcls,
    const void* __restrict__ maskp,
    float4* __restrict__ partial) {

    __shared__ __align__(16) float s_pred[CPB * 30];  // 30 KB: 4 x 7.5 KB wave slices
    __shared__ float s_red[4][4];

    const int t = threadIdx.x;
    const int lane = t & 63;
    const int w = t >> 6;                       // wave id in block
    const int wcell0 = blockIdx.x * CPB + w * 64;

    // ---- (1) flag probe word: first 256 B of mask, identical for all waves ----
    const unsigned fw = ((const unsigned*)maskp)[lane];

    // ---- (2) async stage this wave's pred tile -> private LDS slice ----
    // 64 cells * 30 floats = 480 float4 = 7 full stages + 32-lane tail.
    const float4* pg = (const float4*)(pred + (size_t)wcell0 * 30);
    float4* sp4 = ((float4*)s_pred) + w * 480;  // wave-uniform base
    #pragma unroll
    for (int k = 0; k < 7; ++k)
        stage16(pg + k * 64 + lane, sp4 + k * 64, lane);
    if (lane < 32)
        stage16(pg + 448 + lane, sp4 + 448, lane);

    // ---- (3) tcls into registers (320 float4 per wave, coalesced) ----
    const float4* cg = (const float4*)(tcls + (size_t)wcell0 * 20);
    const float4 c0 = cg[lane];
    const float4 c1 = cg[lane + 64];
    const float4 c2 = cg[lane + 128];
    const float4 c3 = cg[lane + 192];
    const float4 c4 = cg[lane + 256];

    // ---- (4) tbox ----
    const float4 tb = ((const float4*)tbox)[wcell0 + lane];

    // ---- (5) resolve mask dtype from probe (wave-local, no extra kernel) ----
    // int32: all words in {0,1}. float32: {0, 0x3F800000}. uint8(bool): packed
    // 0/1 bytes make words >1 with P ~ 1 per 3 words at 30% density.
    const unsigned long long bGt = __ballot(fw > 1u);
    const unsigned long long bNf = __ballot(fw != 0u && fw != 0x3F800000u);
    const int flag = (bGt == 0ull) ? 0 : ((bNf == 0ull) ? 1 : 2);

    // ---- (6) typed mask load ----
    const int idx = wcell0 + lane;
    bool m;
    if (flag == 0)      m = ((const int*)maskp)[idx] != 0;
    else if (flag == 1) m = ((const float*)maskp)[idx] != 0.0f;
    else                m = ((const unsigned char*)maskp)[idx] != 0;
    const float mf = m ? 1.0f : 0.0f;

    // ---- phase 2: cls loss — tcls regs vs own-wave LDS pred, mf via shfl ----
    // (compiler inserts the vmcnt/lgkmcnt waits; no __syncthreads needed:
    //  this wave issued its own stages and only reads its own slice)
    const float* sw = s_pred + w * 1920;
    float cls = 0.0f;
    {
        #define CLS_STEP(K, CK)                                        \
        {                                                              \
            const int e  = lane + (K) * 64;                            \
            const int c  = e / 5;                                      \
            const int j0 = (e - c * 5) * 4;                            \
            const float* sp = &sw[c * 30 + 10 + j0];                   \
            const float wgt = __shfl(mf, c);                           \
            const float d0 = sp[0] - (CK).x;                           \
            const float d1 = sp[1] - (CK).y;                           \
            const float d2 = sp[2] - (CK).z;                           \
            const float d3 = sp[3] - (CK).w;                           \
            cls += wgt * (d0 * d0 + d1 * d1 + d2 * d2 + d3 * d3);      \
        }
        CLS_STEP(0, c0) CLS_STEP(1, c1) CLS_STEP(2, c2)
        CLS_STEP(3, c3) CLS_STEP(4, c4)
        #undef CLS_STEP
    }

    // ---- phase 3: per-cell box math from own-wave LDS ----
    float pr[10];
    #pragma unroll
    for (int i = 0; i < 10; ++i) pr[i] = sw[lane * 30 + i];

    float noobj = (1.0f - mf) * (pr[4] * pr[4] + pr[9] * pr[9]);

    const float b1x0 = pr[0] * INV_S - 0.5f * pr[2];
    const float b1y0 = pr[1] * INV_S - 0.5f * pr[3];
    const float b1x1 = pr[0] * INV_S + 0.5f * pr[2];
    const float b1y1 = pr[1] * INV_S + 0.5f * pr[3];
    const float b2x0 = pr[5] * INV_S - 0.5f * pr[7];
    const float b2y0 = pr[6] * INV_S - 0.5f * pr[8];
    const float b2x1 = pr[5] * INV_S + 0.5f * pr[7];
    const float b2y1 = pr[6] * INV_S + 0.5f * pr[8];
    const float btx0 = tb.x * INV_S - 0.5f * tb.z;
    const float bty0 = tb.y * INV_S - 0.5f * tb.w;
    const float btx1 = tb.x * INV_S + 0.5f * tb.z;
    const float bty1 = tb.y * INV_S + 0.5f * tb.w;

    const float i1 = iou_xyxy(b1x0, b1y0, b1x1, b1y1, btx0, bty0, btx1, bty1);
    const float i2 = iou_xyxy(b2x0, b2y0, b2x1, b2y1, btx0, bty0, btx1, bty1);

    const bool take1 = i1 > i2;
    const float best_iou = take1 ? i1 : i2;
    const float bx = take1 ? pr[0] : pr[5];
    const float by = take1 ? pr[1] : pr[6];
    const float bw = take1 ? pr[2] : pr[7];
    const float bh = take1 ? pr[3] : pr[8];
    const float bc = take1 ? pr[4] : pr[9];

    const float dx = bx - tb.x;
    const float dy = by - tb.y;
    const float pw = m ? sqrtf(bw) : 1.0f;
    const float ph = m ? sqrtf(bh) : 1.0f;
    const float tw = m ? sqrtf(tb.z) : 1.0f;
    const float th = m ? sqrtf(tb.w) : 1.0f;
    float reg = mf * (dx * dx + dy * dy)
              + mf * ((pw - tw) * (pw - tw) + (ph - th) * (ph - th));

    const float dc = bc - best_iou;
    float conf = mf * dc * dc;

    // ---- in-wave reduction (no cross-wave coupling) ----
    #pragma unroll
    for (int off = 32; off > 0; off >>= 1) {
        reg   += __shfl_down(reg,   off);
        conf  += __shfl_down(conf,  off);
        noobj += __shfl_down(noobj, off);
        cls   += __shfl_down(cls,   off);
    }
    if (lane == 0) {
        s_red[0][w] = reg; s_red[1][w] = conf;
        s_red[2][w] = noobj; s_red[3][w] = cls;
    }
    __syncthreads();   // ONLY barrier: final partial combine, all memory done
    if (t == 0) {
        partial[blockIdx.x] = make_float4(s_red[0][0] + s_red[0][1] + s_red[0][2] + s_red[0][3],
                                          s_red[1][0] + s_red[1][1] + s_red[1][2] + s_red[1][3],
                                          s_red[2][0] + s_red[2][1] + s_red[2][2] + s_red[2][3],
                                          s_red[3][0] + s_red[3][1] + s_red[3][2] + s_red[3][3]);
    }
}

// ---------------------------------------------------------------------------
// Kernel 2: finalize — reduce 3136 block partials (double accum), normalize.
// ---------------------------------------------------------------------------
__global__ __launch_bounds__(1024) void yolo_finalize(
    const float4* __restrict__ partial,
    float* __restrict__ out) {
    const int t = threadIdx.x;
    double r = 0.0, cf = 0.0, no = 0.0, cl = 0.0;
    for (int i = t; i < NBLOCKS; i += 1024) {
        const float4 p = partial[i];
        r += (double)p.x; cf += (double)p.y; no += (double)p.z; cl += (double)p.w;
    }
    #pragma unroll
    for (int off = 32; off > 0; off >>= 1) {
        r  += __shfl_down(r,  off);
        cf += __shfl_down(cf, off);
        no += __shfl_down(no, off);
        cl += __shfl_down(cl, off);
    }
    __shared__ double s[4][16];
    const int lane = t & 63;
    const int wid  = t >> 6;
    if (lane == 0) { s[0][wid] = r; s[1][wid] = cf; s[2][wid] = no; s[3][wid] = cl; }
    __syncthreads();
    if (t == 0) {
        double R = 0, CF = 0, NO = 0, CL = 0;
        #pragma unroll
        for (int w = 0; w < 16; ++w) { R += s[0][w]; CF += s[1][w]; NO += s[2][w]; CL += s[3][w]; }
        const float invN = 1.0f / (float)N_BATCH;
        const float reg   = (float)R  * invN;
        const float conf  = (float)CF * invN;
        const float noobj = (float)NO * invN;
        const float cls   = (float)CL * invN;
        out[0] = 5.0f * reg + conf + 0.5f * noobj + cls;
        out[1] = reg;
        out[2] = conf;
        out[3] = noobj;
        out[4] = cls;
    }
}

extern "C" void kernel_launch(void* const* d_in, const int* in_sizes, int n_in,
                              void* d_out, int out_size, void* d_ws, size_t ws_size,
                              hipStream_t stream) {
    const float* pred = (const float*)d_in[0];
    const float* tbox = (const float*)d_in[1];
    const float* tcls = (const float*)d_in[2];
    const void*  mask = (const void*)d_in[3];
    float* out = (float*)d_out;

    float4* partial = (float4*)d_ws;   // 3136 * 16 B = 50 KB

    yolo_loss_main<<<NBLOCKS, 256, 0, stream>>>(pred, tbox, tcls, mask, partial);
    yolo_finalize<<<1, 1024, 0, stream>>>(partial, out);
}